// Round 10
// baseline (535.257 us; speedup 1.0000x reference)
//
#include <hip/hip_runtime.h>
#include <hip/hip_bf16.h>

// Problem constants
#define B_   4
#define N_   4096
#define IND  512
#define ATT  64
#define QKD  128   // 2*ATT

// adj@k split-K
#define KSPLIT 4
#define KCHUNK 1024   // 4096 / KSPLIT; 32 slabs of 32 k each

typedef __attribute__((ext_vector_type(8))) short short8v;  // 8 bf16
typedef __attribute__((ext_vector_type(4))) float f32x4;

__device__ __forceinline__ void f8_to_bf16_hilo(const float4& v0, const float4& v1,
                                                short8v& hi, short8v& lo) {
  union { short8v v; unsigned short u[8]; } h, l;
  const float av[8] = {v0.x, v0.y, v0.z, v0.w, v1.x, v1.y, v1.z, v1.w};
#pragma unroll
  for (int j = 0; j < 8; ++j) {
    const unsigned short hu = (unsigned short)(__float_as_uint(av[j]) >> 16);
    const float fh = __uint_as_float((unsigned)hu << 16);
    h.u[j] = hu;
    l.u[j] = (unsigned short)(__float_as_uint(av[j] - fh) >> 16);
  }
  hi = h.v; lo = l.v;
}

// ---------------------------------------------------------------------------
// pack_adj: adj (binary f32, 268 MB) -> bitmask bytes (8.4 MB).
// byte i covers floats [8i, 8i+8); bit j = (adj[8i+j] != 0).
// Pure streaming, grid-stride, no dependencies -> trivially BW-bound (~45 us).
// This is the ONLY kernel that reads adj; the MFMA kernel reads 8.4 MB.
// ---------------------------------------------------------------------------
__global__ __launch_bounds__(256)
void pack_adj(const float* __restrict__ adj, unsigned char* __restrict__ mask) {
  const size_t total = (size_t)B_ * N_ * (N_ / 8);   // 8.4M bytes
  size_t i = (size_t)blockIdx.x * 256 + threadIdx.x;
  const size_t stride = (size_t)gridDim.x * 256;
  for (; i < total; i += stride) {
    const float4 v0 = *(const float4*)(adj + i * 8);
    const float4 v1 = *(const float4*)(adj + i * 8 + 4);
    unsigned b = 0;
    b |= (v0.x != 0.f) ? 1u   : 0u;
    b |= (v0.y != 0.f) ? 2u   : 0u;
    b |= (v0.z != 0.f) ? 4u   : 0u;
    b |= (v0.w != 0.f) ? 8u   : 0u;
    b |= (v1.x != 0.f) ? 16u  : 0u;
    b |= (v1.y != 0.f) ? 32u  : 0u;
    b |= (v1.z != 0.f) ? 64u  : 0u;
    b |= (v1.w != 0.f) ? 128u : 0u;
    mask[i] = (unsigned char)b;
  }
}

// ---------------------------------------------------------------------------
// prep_frag: row-major f32 src[nrows][512] -> frag-linear bf16 hi/lo table:
//   dst[((ct*16 + slab)*2 + h)*512 + lane*8 + j]
//     = bf16_h( src[ct*16 + (lane&15)][slab*32 + (lane>>4)*8 + j] )
// (A-frag AND B-frag lane mapping for mfma_f32_16x16x32_bf16; r3-r8 verified.)
// ---------------------------------------------------------------------------
__global__ __launch_bounds__(256)
void prep_frag(const float* __restrict__ src, unsigned short* __restrict__ dst,
               int nct) {
  const int wid = threadIdx.x >> 6, lane = threadIdx.x & 63;
  const int ct = blockIdx.x * 4 + wid;
  if (ct >= nct) return;
  const float* s = src + ((size_t)ct * 16 + (lane & 15)) * IND + ((lane >> 4) << 3);
  unsigned short* d = dst + (size_t)ct * 16 * 2 * 512 + (size_t)lane * 8;
#pragma unroll 4
  for (int slab = 0; slab < 16; ++slab) {
    const float4 v0 = *(const float4*)(s + slab * 32);
    const float4 v1 = *(const float4*)(s + slab * 32 + 4);
    short8v hv, lv;
    f8_to_bf16_hilo(v0, v1, hv, lv);
    *(short8v*)(d + (size_t)slab * 2 * 512)       = hv;
    *(short8v*)(d + (size_t)slab * 2 * 512 + 512) = lv;
  }
}

// ---------------------------------------------------------------------------
// gemm_mfma: C = X @ W^T via bf16 hi/lo MFMA, 3-term (err ~2^-16).
// Optional fused row-scale epilogue (wsc != nullptr): C[row][:] *= wsc[row].
// Wave: 16 rows x 128 cols; block 64 rows; grid (M/64, Nout/128). [r6/r8-passing]
// ---------------------------------------------------------------------------
__global__ __launch_bounds__(256, 2)
void gemm_mfma(const unsigned short* __restrict__ xf,
               const unsigned short* __restrict__ wf,
               float* __restrict__ C, int Nout,
               const float* __restrict__ wsc) {
  const int lane = threadIdx.x & 63;
  const int wid  = threadIdx.x >> 6;
  const int g0   = blockIdx.x * 64 + wid * 16;
  const int mt   = g0 >> 4;
  const int ct0  = blockIdx.y * 8;

  const unsigned short* xb = xf + (size_t)mt * 16 * 2 * 512 + (size_t)lane * 8;
  const unsigned short* wb = wf + (size_t)ct0 * 16 * 2 * 512 + (size_t)lane * 8;

  f32x4 acc[8] = {{0.f,0.f,0.f,0.f},{0.f,0.f,0.f,0.f},{0.f,0.f,0.f,0.f},
                  {0.f,0.f,0.f,0.f},{0.f,0.f,0.f,0.f},{0.f,0.f,0.f,0.f},
                  {0.f,0.f,0.f,0.f},{0.f,0.f,0.f,0.f}};

  short8v axh = *(const short8v*)(xb);
  short8v axl = *(const short8v*)(xb + 512);

  for (int slab = 0; slab < 16; ++slab) {
    const int sn = (slab < 15) ? slab + 1 : 15;
    const short8v nxh = *(const short8v*)(xb + (size_t)sn * 1024);
    const short8v nxl = *(const short8v*)(xb + (size_t)sn * 1024 + 512);

#pragma unroll
    for (int c = 0; c < 8; ++c) {
      const unsigned short* wp = wb + ((size_t)(c * 16 + slab) * 2) * 512;
      const short8v bh = *(const short8v*)(wp);
      const short8v bl = *(const short8v*)(wp + 512);
      acc[c] = __builtin_amdgcn_mfma_f32_16x16x32_bf16(axh, bh, acc[c], 0, 0, 0);
      acc[c] = __builtin_amdgcn_mfma_f32_16x16x32_bf16(axl, bh, acc[c], 0, 0, 0);
      acc[c] = __builtin_amdgcn_mfma_f32_16x16x32_bf16(axh, bl, acc[c], 0, 0, 0);
    }
    axh = nxh; axl = nxl;
  }

  float* outp = C + ((size_t)g0 + ((lane >> 4) << 2)) * Nout + ct0 * 16 + (lane & 15);
#pragma unroll
  for (int r = 0; r < 4; ++r) {
    const float s = wsc ? wsc[g0 + ((lane >> 4) << 2) + r] : 1.0f;
#pragma unroll
    for (int c = 0; c < 8; ++c)
      outp[(size_t)r * Nout + c * 16] = acc[c][r] * s;
  }
}

// ---------------------------------------------------------------------------
// prep_k: k part of qk (f32) -> frag-linear bf16 hi/lo table:
//   ktf[(((b*128 + slab)*4 + c)*2 + h)*512 + lane*8 + j]   [r5-r8 verified]
// ---------------------------------------------------------------------------
__global__ __launch_bounds__(256)
void prep_k(const float* __restrict__ qk, unsigned short* __restrict__ ktf) {
  __shared__ unsigned short sh[32][68];
  __shared__ unsigned short sl[32][68];
  const int b    = blockIdx.x >> 7;
  const int slab = blockIdx.x & 127;
  const int t = threadIdx.x;

#pragma unroll
  for (int i = 0; i < 2; ++i) {
    const int f = t + i * 256;
    const int ml  = f >> 4;
    const int ch4 = (f & 15) << 2;
    const float4 v = *(const float4*)(qk +
        ((size_t)b * N_ + slab * 32 + ml) * QKD + ATT + ch4);
    const float vv[4] = {v.x, v.y, v.z, v.w};
#pragma unroll
    for (int j = 0; j < 4; ++j) {
      const unsigned short hi = (unsigned short)(__float_as_uint(vv[j]) >> 16);
      const float fhi = __uint_as_float((unsigned)hi << 16);
      const unsigned short lo = (unsigned short)(__float_as_uint(vv[j] - fhi) >> 16);
      sh[ml][ch4 + j] = hi;
      sl[ml][ch4 + j] = lo;
    }
  }
  __syncthreads();

  const int lane = t & 63;
  const int c    = t >> 6;
  const int mb   = (lane >> 4) << 3;
  const int ch   = c * 16 + (lane & 15);
  unsigned short* outb = ktf +
      (((size_t)(b * 128 + slab) * 4 + c) * 2) * 512 + (size_t)lane * 8;
  union { short8v v; unsigned short u[8]; } hv, lv;
#pragma unroll
  for (int j = 0; j < 8; ++j) {
    hv.u[j] = sh[mb + j][ch];
    lv.u[j] = sl[mb + j][ch];
  }
  *(short8v*)(outb)       = hv.v;
  *(short8v*)(outb + 512) = lv.v;
}

// ---------------------------------------------------------------------------
// adjk_bits: ka_partial = adj @ (k_hi + k_lo) with A rebuilt from the bitmask.
// No LDS, no barriers, no A traffic: A-frag = 8 bits of one mask u32 expanded
// to bf16 {0,1} in registers (~16 VALU per frag). B-frags stream from the
// L2-resident frag-linear ktf. Wave: 16 rows x 64 ch; block 64 rows; grid
// (256, KSPLIT=4) = 1024 blocks, 4 waves/SIMD. MFMA floor 8.3 us.
// C/D: col = lane&15, row = (lane>>4)*4 + r   [r3-r8 verified].
// ---------------------------------------------------------------------------
__global__ __launch_bounds__(256, 4)
void adjk_bits(const unsigned char* __restrict__ mask,
               const unsigned short* __restrict__ ktf,
               float* __restrict__ kapart) {
  const int lane = threadIdx.x & 63;
  const int wid  = threadIdx.x >> 6;
  const int g0   = blockIdx.x * 64 + wid * 16;   // 16-row tile per wave
  const int b    = g0 >> 12;
  const int split = blockIdx.y;                  // 0..3
  const int slab0 = split * 32;

  const int lr  = lane >> 4;     // 0..3
  const int cch = lane & 15;
  const int bitoff = lr << 3;

  // mask row for this lane's A-row; 128 u32 words per row, words slab0..slab0+31
  const unsigned int* mrow =
      (const unsigned int*)mask + (size_t)(g0 + cch) * (N_ / 32) + slab0;
  const unsigned short* kbase =
      ktf + ((size_t)b * 128 + slab0) * 4096 + (size_t)lane * 8;

  f32x4 acc[4] = {{0.f,0.f,0.f,0.f},{0.f,0.f,0.f,0.f},
                  {0.f,0.f,0.f,0.f},{0.f,0.f,0.f,0.f}};

#pragma unroll 4
  for (int s = 0; s < 32; ++s) {
    const unsigned int word = mrow[s];
    const unsigned int byte = (word >> bitoff) & 0xffu;
    union { short8v v; unsigned short u[8]; } af;
#pragma unroll
    for (int j = 0; j < 8; ++j)
      af.u[j] = ((byte >> j) & 1u) ? (unsigned short)0x3F80 : (unsigned short)0;

    const unsigned short* kb = kbase + (size_t)s * 4096;
    const short8v b0h = *(const short8v*)(kb);
    const short8v b0l = *(const short8v*)(kb + 512);
    const short8v b1h = *(const short8v*)(kb + 1024);
    const short8v b1l = *(const short8v*)(kb + 1536);
    const short8v b2h = *(const short8v*)(kb + 2048);
    const short8v b2l = *(const short8v*)(kb + 2560);
    const short8v b3h = *(const short8v*)(kb + 3072);
    const short8v b3l = *(const short8v*)(kb + 3584);

    acc[0] = __builtin_amdgcn_mfma_f32_16x16x32_bf16(af.v, b0h, acc[0], 0, 0, 0);
    acc[0] = __builtin_amdgcn_mfma_f32_16x16x32_bf16(af.v, b0l, acc[0], 0, 0, 0);
    acc[1] = __builtin_amdgcn_mfma_f32_16x16x32_bf16(af.v, b1h, acc[1], 0, 0, 0);
    acc[1] = __builtin_amdgcn_mfma_f32_16x16x32_bf16(af.v, b1l, acc[1], 0, 0, 0);
    acc[2] = __builtin_amdgcn_mfma_f32_16x16x32_bf16(af.v, b2h, acc[2], 0, 0, 0);
    acc[2] = __builtin_amdgcn_mfma_f32_16x16x32_bf16(af.v, b2l, acc[2], 0, 0, 0);
    acc[3] = __builtin_amdgcn_mfma_f32_16x16x32_bf16(af.v, b3h, acc[3], 0, 0, 0);
    acc[3] = __builtin_amdgcn_mfma_f32_16x16x32_bf16(af.v, b3l, acc[3], 0, 0, 0);
  }

  // write partials: kapart[split][row][ch]
  float* outp = kapart +
      ((size_t)split * (B_ * N_) + g0 + (lr << 2)) * ATT + cch;
#pragma unroll
  for (int c = 0; c < 4; ++c)
#pragma unroll
    for (int r = 0; r < 4; ++r)
      outp[(size_t)r * ATT + c * 16] = acc[c][r];
}

// ---------------------------------------------------------------------------
// wpre[row] = (1/8) * q[row] . (sum of KSPLIT ka partials)  — one wave/row
// ---------------------------------------------------------------------------
__global__ __launch_bounds__(256)
void qdot(const float* __restrict__ qk, const float* __restrict__ kapart,
          float* __restrict__ wpre) {
  const int wid  = threadIdx.x >> 6;
  const int lane = threadIdx.x & 63;
  const int row  = blockIdx.x * 4 + wid;

  float ka = 0.f;
#pragma unroll
  for (int s = 0; s < KSPLIT; ++s)
    ka += kapart[((size_t)s * B_ * N_ + row) * ATT + lane];

  const float q = qk[(size_t)row * QKD + lane];
  float val = q * ka;
#pragma unroll
  for (int off = 32; off; off >>= 1) val += __shfl_xor(val, off);
  if (lane == 0) wpre[row] = val * 0.125f;
}

// ---------------------------------------------------------------------------
// Softmax over the bag dimension (N=4096) per batch, in-place.
// ---------------------------------------------------------------------------
__global__ __launch_bounds__(256)
void softmax_bag(float* __restrict__ w) {
  __shared__ float red[256];
  const int b = blockIdx.x;
  float* wb = w + (size_t)b * N_;
  const int t = threadIdx.x;

  float vals[16];
  float mx = -1e30f;
#pragma unroll
  for (int i = 0; i < 16; ++i) {
    vals[i] = wb[t + i * 256];
    mx = fmaxf(mx, vals[i]);
  }
  red[t] = mx; __syncthreads();
  for (int s = 128; s; s >>= 1) {
    if (t < s) red[t] = fmaxf(red[t], red[t + s]);
    __syncthreads();
  }
  mx = red[0];
  __syncthreads();

  float sum = 0.f;
#pragma unroll
  for (int i = 0; i < 16; ++i) {
    vals[i] = expf(vals[i] - mx);
    sum += vals[i];
  }
  red[t] = sum; __syncthreads();
  for (int s = 128; s; s >>= 1) {
    if (t < s) red[t] += red[t + s];
    __syncthreads();
  }
  const float inv = 1.f / red[0];
#pragma unroll
  for (int i = 0; i < 16; ++i) wb[t + i * 256] = vals[i] * inv;
}

extern "C" void kernel_launch(void* const* d_in, const int* in_sizes, int n_in,
                              void* d_out, int out_size, void* d_ws, size_t ws_size,
                              hipStream_t stream) {
  const float* x    = (const float*)d_in[0];   // (B,N,512)
  const float* adj  = (const float*)d_in[1];   // (B,N,N)
  const float* W_qk = (const float*)d_in[2];   // (128,512)
  const float* W_v  = (const float*)d_in[3];   // (512,512)
  float* out = (float*)d_out;                  // (B,N,512)

  float* qk     = (float*)d_ws;                              // 8 MB
  float* kapart = qk + (size_t)B_ * N_ * QKD;                // 16 MB (KSPLIT=4)
  float* wpre   = kapart + (size_t)KSPLIT * B_ * N_ * ATT;   // 64 KB
  unsigned short* ktf  = (unsigned short*)(wpre + B_ * N_);  // 4 MB frag-linear k
  unsigned short* xft  = ktf + (size_t)B_ * 128 * 4096;      // 33.5 MB frag x
  unsigned short* wvf  = xft + (size_t)1024 * 16 * 2 * 512;  // 1 MB frag W_v
  unsigned short* wqkf = wvf + (size_t)32 * 16 * 2 * 512;    // 256 KB frag W_qk
  unsigned char* mask  = (unsigned char*)(wqkf + (size_t)8 * 16 * 2 * 512); // 8.4 MB

  const int M = B_ * N_;  // 16384

  // adj -> bitmask (the only reader of the 268 MB adj; pure streaming)
  pack_adj<<<2048, 256, 0, stream>>>(adj, mask);

  // frag-linear bf16 hi/lo tables for X, W_v, W_qk
  prep_frag<<<256, 256, 0, stream>>>(x, xft, 1024);
  prep_frag<<<8, 256, 0, stream>>>(W_v, wvf, 32);
  prep_frag<<<2, 256, 0, stream>>>(W_qk, wqkf, 8);

  // qk = x @ W_qk^T
  {
    dim3 grid(M / 64, QKD / 128);
    gemm_mfma<<<grid, 256, 0, stream>>>(xft, wqkf, qk, QKD, nullptr);
  }
  // k -> frag-linear bf16 hi/lo table
  prep_k<<<B_ * 128, 256, 0, stream>>>(qk, ktf);
  // ka partials = (bitmask adj) @ k via register-expanded MFMA
  {
    dim3 grid(M / 64, KSPLIT);
    adjk_bits<<<grid, 256, 0, stream>>>(mask, ktf, kapart);
  }
  // wpre = q . ka / 8
  qdot<<<M / 4, 256, 0, stream>>>(qk, kapart, wpre);
  // softmax over bag dim
  softmax_bag<<<B_, 256, 0, stream>>>(wpre);
  // out = (x @ W_v^T) * w   (scale fused into epilogue)
  {
    dim3 grid(M / 64, IND / 128);
    gemm_mfma<<<grid, 256, 0, stream>>>(xft, wvf, out, IND, wpre);
  }
}